// Round 6
// baseline (523.515 us; speedup 1.0000x reference)
//
#include <hip/hip_runtime.h>
#include <math.h>

#define NN 200000      // nodes
#define NE 6400000     // edges
#define FIN 100        // input feature dim
#define MR 10000       // sampled rows (NN/20)
#define BSH 14         // coarse bucket shift (16384-node windows)
#define NBK 13         // ceil(NN / 16384)
#define NSB 1563       // ceil(NN / 128) sub-buckets of 128 nodes
#define EPB 4096       // edges per block in stage A/B
#define STCAP 6144     // LDS sort capacity in aggfused
#define SAMPCAP 1024   // per-block sampled-edge LDS staging (mean 210, sd 14)
#define SAMPG_CAP (1<<20)  // global sampled list capacity (mean 328K)

// ---------- float <-> monotonic-uint encoding for atomic min/max ----------
static __device__ __forceinline__ unsigned enc_f(float f){
  unsigned u = __float_as_uint(f);
  return (u & 0x80000000u) ? ~u : (u | 0x80000000u);
}
static __device__ __forceinline__ float dec_f(unsigned u){
  return (u & 0x80000000u) ? __uint_as_float(u ^ 0x80000000u) : __uint_as_float(~u);
}
// ---------- fp32 <-> bf16 (round-nearest-even) ----------
static __device__ __forceinline__ unsigned short f2bf(float f){
  unsigned u = __float_as_uint(f);
  return (unsigned short)((u + 0x7fffu + ((u >> 16) & 1u)) >> 16);
}
static __device__ __forceinline__ float bf2f(unsigned short h){
  return __uint_as_float(((unsigned)h) << 16);
}

// ---------- init ----------
__global__ void k_init(int* bcnt2, float* gacc, unsigned* mm, int* sampCnt){
  int i = blockIdx.x*blockDim.x + threadIdx.x;
  if(i < NSB) bcnt2[i] = 0;
  if(i < 2*MR) gacc[i] = 0.f;
  if(i == 0){ mm[0] = 0xFFFFFFFFu; mm[1] = 0u; sampCnt[0] = 0; }
}

// ---------- sub-bucket histogram (dst>>7), LDS-staged ----------
__global__ __launch_bounds__(256) void k_hist(const int4* __restrict__ dst4,
                                              int* __restrict__ bcnt2){
  __shared__ int sh[NSB];
  for(int i=threadIdx.x;i<NSB;i+=256) sh[i]=0;
  __syncthreads();
  const int nq = NE/4;
  for(int q = blockIdx.x*256 + threadIdx.x; q < nq; q += gridDim.x*256){
    int4 d = dst4[q];
    atomicAdd(&sh[d.x>>7],1); atomicAdd(&sh[d.y>>7],1);
    atomicAdd(&sh[d.z>>7],1); atomicAdd(&sh[d.w>>7],1);
  }
  __syncthreads();
  for(int i=threadIdx.x;i<NSB;i+=256){ int v=sh[i]; if(v) atomicAdd(&bcnt2[i],v); }
}

// ---------- scan sub-bucket counts -> bases/cursors; derive bucket bases ----------
__global__ void k_scan2(const int* __restrict__ bcnt2, int* bbase2, int* bcur2,
                        int* bbase1, int* bcur1){
  __shared__ int part[256];
  int t = threadIdx.x;
  int base = t*7;
  int loc[7]; int s = 0;
  #pragma unroll
  for(int j=0;j<7;j++){ int i = base+j; loc[j] = (i<NSB)? bcnt2[i] : 0; s += loc[j]; }
  part[t] = s; __syncthreads();
  for(int o=1;o<256;o<<=1){
    int x = (t>=o)? part[t-o] : 0;
    __syncthreads();
    part[t] += x;
    __syncthreads();
  }
  int run = part[t] - s;
  #pragma unroll
  for(int j=0;j<7;j++){
    int i = base+j;
    if(i<NSB){ bbase2[i] = run; bcur2[i] = run; }
    run += loc[j];
  }
  if(t==0) bbase2[NSB] = NE;
  __syncthreads();
  if(t < NBK){ int v = bbase2[t*128]; bbase1[t] = v; bcur1[t] = v; }
  if(t == NBK){ bbase1[NBK] = NE; }
}

// ---------- stage A: 13-way partition, ballot-ranked (no per-edge atomics) ----------
// pack = (dst_local14 << 18) | src. Also emits compact sampled-edge list
// (dst%20==0) as (dst/20)<<18 | src for layer-2.
__global__ __launch_bounds__(256) void k_stageA(const int* __restrict__ src,
                                                const int* __restrict__ dst,
                                                int* __restrict__ bcur1,
                                                unsigned* __restrict__ bucket1,
                                                int* __restrict__ sampCnt,
                                                unsigned* __restrict__ sampG){
  __shared__ unsigned stage[EPB];          // 16 KB
  __shared__ unsigned char binOf[EPB];     // 4 KB
  __shared__ unsigned samp[SAMPCAP];       // 4 KB
  __shared__ int wtot[4][16], woff[4][16], bst[16], cnt16[16], gbase[16];
  __shared__ int scnt, sbase;
  int t = threadIdx.x, lane = t & 63, wv = t >> 6;
  int ebase = blockIdx.x*EPB;
  int nEdge = min(EPB, NE - ebase);        // multiple of 4 always
  if(t == 0) scnt = 0;
  __syncthreads();

  const int4* s4 = (const int4*)(src + ebase);
  const int4* d4 = (const int4*)(dst + ebase);
  unsigned pk[16]; int bb[16]; int posw[16];
  int wcnt[13];
  #pragma unroll
  for(int b=0;b<13;b++) wcnt[b]=0;
  unsigned long long lt = (1ull<<lane)-1ull;

  #pragma unroll
  for(int j=0;j<4;j++){
    int q = t + j*256, eo = q*4;
    if(eo < nEdge){
      int4 s = s4[q]; int4 d = d4[q];
      int ds[4]={d.x,d.y,d.z,d.w}, ss[4]={s.x,s.y,s.z,s.w};
      #pragma unroll
      for(int k=0;k<4;k++){
        int r = j*4+k;
        bb[r] = ds[k]>>BSH;
        pk[r] = ((unsigned)(ds[k] & 16383) << 18) | (unsigned)ss[k];
      }
    } else {
      bb[j*4+0]=bb[j*4+1]=bb[j*4+2]=bb[j*4+3] = 15;   // invalid sentinel
    }
  }
  // wave-level ballot ranking: 16 rounds x 13 bins
  #pragma unroll
  for(int r=0;r<16;r++){
    int br = bb[r];
    #pragma unroll
    for(int b=0;b<13;b++){
      unsigned long long m = __ballot(br==b);
      if(br==b) posw[r] = wcnt[b] + (int)__popcll(m & lt);
      wcnt[b] += (int)__popcll(m);
    }
  }
  #pragma unroll
  for(int b=0;b<13;b++) if(lane==b) wtot[wv][b] = wcnt[b];
  __syncthreads();
  if(t == 0){
    int run = 0;
    #pragma unroll
    for(int b=0;b<13;b++){
      int c0=wtot[0][b], c1=wtot[1][b], c2=wtot[2][b], c3=wtot[3][b];
      int tot = c0+c1+c2+c3;
      cnt16[b]=tot; bst[b]=run;
      woff[0][b]=run; woff[1][b]=run+c0; woff[2][b]=run+c0+c1; woff[3][b]=run+c0+c1+c2;
      run += tot;
    }
  }
  __syncthreads();
  if(t < NBK && cnt16[t]) gbase[t] = atomicAdd(&bcur1[t], cnt16[t]);
  // scatter to LDS
  #pragma unroll
  for(int r=0;r<16;r++){
    if(bb[r] < 13){
      int p = woff[wv][bb[r]] + posw[r];
      stage[p] = pk[r]; binOf[p] = (unsigned char)bb[r];
    }
  }
  // sampled-edge emission (wave-aggregated)
  #pragma unroll
  for(int r=0;r<16;r++){
    int dg = (bb[r]<<BSH) | (int)(pk[r]>>18);
    bool sp = (bb[r] < 13) && (dg % 20 == 0);
    unsigned long long m = __ballot(sp);
    if(m){
      int ldr = __ffsll((unsigned long long)m) - 1;
      int wb = 0;
      if(lane == ldr) wb = atomicAdd(&scnt, (int)__popcll(m));
      wb = __shfl(wb, ldr);
      if(sp){
        int p = wb + (int)__popcll(m & lt);
        unsigned enc2 = ((unsigned)(dg/20) << 18) | (pk[r] & 0x3FFFFu);
        if(p < SAMPCAP) samp[p] = enc2;
        else { int gp = atomicAdd(sampCnt, 1); if(gp < SAMPG_CAP) sampG[gp] = enc2; }
      }
    }
  }
  __syncthreads();
  if(t == 0) sbase = atomicAdd(sampCnt, min(scnt, SAMPCAP));
  __syncthreads();
  {
    int nS = min(scnt, SAMPCAP);
    for(int k=t; k<nS; k+=256){
      int gp = sbase + k;
      if(gp < SAMPG_CAP) sampG[gp] = samp[k];
    }
  }
  // copy-out: coalesced per-bucket runs
  for(int k=t; k<nEdge; k+=256){
    int b = binOf[k];
    bucket1[gbase[b] + (k - bst[b])] = stage[k];
  }
}

// ---------- stage B: refine buckets into 1563 sub-buckets (128 nodes) ----------
// pack = (dst_local7 << 18) | src
__global__ __launch_bounds__(256) void k_stageB(const unsigned* __restrict__ bucket1,
                                                const int* __restrict__ bbase1,
                                                int* __restrict__ bcur2,
                                                unsigned* __restrict__ bucket2){
  __shared__ unsigned stage[EPB];
  __shared__ unsigned char binOf[EPB];
  __shared__ int cnt[256], bst[256], gbase[256];
  __shared__ int bb1[NBK+1];
  int t = threadIdx.x;
  int ebase = blockIdx.x*EPB;
  int nEdge = min(EPB, NE - ebase);
  if(t < NBK) bb1[t] = bbase1[t];
  if(t == NBK) bb1[NBK] = NE;
  cnt[t] = 0;
  __syncthreads();
  int bF = 0;
  while(bF < NBK-1 && bb1[bF+1] <= ebase) bF++;
  int sb0 = bF << 7;
  unsigned pk[16]; int ln[16], rr[16];
  const uint4* e4 = (const uint4*)(bucket1 + ebase);
  int b = bF;
  #pragma unroll
  for(int j=0;j<4;j++){
    int q = t + j*256, eo = q*4;
    if(eo < nEdge){
      uint4 e = e4[q];
      unsigned ev[4] = {e.x, e.y, e.z, e.w};
      #pragma unroll
      for(int k=0;k<4;k++){
        int gidx = ebase + eo + k;
        while(b < NBK-1 && bb1[b+1] <= gidx) b++;
        unsigned p = ev[k];
        unsigned dl14 = p >> 18;
        int sbl = ((b<<7) | (int)(dl14>>7)) - sb0;   // 0..255
        pk[j*4+k] = ((dl14 & 127u) << 18) | (p & 0x3FFFFu);
        ln[j*4+k] = sbl;
        rr[j*4+k] = atomicAdd(&cnt[sbl], 1);
      }
    } else {
      rr[j*4+0]=rr[j*4+1]=rr[j*4+2]=rr[j*4+3] = -1;
    }
  }
  __syncthreads();
  if(t == 0){
    int run = 0;
    for(int i=0;i<256;i++){ bst[i] = run; run += cnt[i]; }
  }
  __syncthreads();
  {
    int sbg = sb0 + t;
    if(cnt[t] && sbg < NSB) gbase[t] = atomicAdd(&bcur2[sbg], cnt[t]);
  }
  #pragma unroll
  for(int j=0;j<16;j++){
    if(rr[j] >= 0){
      int p = bst[ln[j]] + rr[j];
      stage[p] = pk[j]; binOf[p] = (unsigned char)ln[j];
    }
  }
  __syncthreads();
  for(int k=t; k<nEdge; k+=256){
    int bin = binOf[k];
    bucket2[gbase[bin] + (k - bst[bin])] = stage[k];
  }
}

// ---------- fused: per-node degree -> dinv, then coalesced LDS-staged x@W1 ----------
// one block per 128-node sub-bucket; x-tile staged in LDS (pad 101 -> conflict-free)
__global__ __launch_bounds__(256) void k_cntxw1(const unsigned* __restrict__ bucket2,
                                                const int* __restrict__ bbase2,
                                                const float* __restrict__ x,
                                                const float* __restrict__ W1,
                                                float* __restrict__ dinv,
                                                unsigned short* __restrict__ h1b){
  __shared__ float xs[128*101];   // 51.7 KB
  __shared__ float w1s[FIN*16];   // 6.4 KB
  __shared__ int c[128];
  int t = threadIdx.x, sb = blockIdx.x;
  int row0 = sb*128;
  int nrow = min(128, NN - row0);
  for(int i=t; i<FIN*16; i+=256) w1s[i] = W1[i];
  if(t < 128) c[t] = 0;
  __syncthreads();
  // degree count for these 128 nodes
  int e0 = bbase2[sb], e1 = bbase2[sb+1];
  for(int i=e0+t; i<e1; i+=256) atomicAdd(&c[bucket2[i]>>18], 1);
  // stage x rows coalesced (flat float4 indexing; row stride 100 floats = 25 f4)
  {
    const float4* xg = (const float4*)x;
    int n4 = nrow*25;
    for(int i=t; i<n4; i+=256){
      float4 v = xg[row0*25 + i];
      int r = i/25, c4 = i - r*25;
      float* p = &xs[r*101 + c4*4];
      p[0]=v.x; p[1]=v.y; p[2]=v.z; p[3]=v.w;
    }
  }
  __syncthreads();
  // 2 threads per row, 8 cols each
  int r = t >> 1, half = t & 1;
  if(r < nrow){
    float dv = rsqrtf((float)(c[r] + 1));
    if(half == 0) dinv[row0 + r] = dv;
    float acc[8];
    #pragma unroll
    for(int j=0;j<8;j++) acc[j] = 0.f;
    const float* xr = &xs[r*101];
    #pragma unroll 4
    for(int k=0;k<FIN;k++){
      float xv = xr[k];
      const float* w = &w1s[k*16 + half*8];
      #pragma unroll
      for(int j=0;j<8;j++) acc[j] += xv * w[j];
    }
    unsigned p[4];
    #pragma unroll
    for(int j=0;j<4;j++){
      p[j] = (unsigned)f2bf(acc[2*j]*dv) | ((unsigned)f2bf(acc[2*j+1]*dv) << 16);
    }
    ((uint4*)(h1b + (size_t)(row0+r)*16))[half] = make_uint4(p[0],p[1],p[2],p[3]);
  }
}

// ---------- fused layer-1 aggregation per sub-bucket + bias/relu/@W2 ----------
__global__ __launch_bounds__(512) void k_aggfused(const unsigned* __restrict__ bucket2,
                                                  const int* __restrict__ bbase2,
                                                  const float* __restrict__ dinv,
                                                  const unsigned short* __restrict__ h1b,
                                                  const float* __restrict__ b1,
                                                  const float* __restrict__ W2,
                                                  float* __restrict__ h2s){
  __shared__ unsigned srt[STCAP];          // 24 KB
  __shared__ int cnt[128], coff[129], cur[128];
  __shared__ int wsum0;
  int t = threadIdx.x, sb = blockIdx.x;
  int e0 = bbase2[sb], e1 = bbase2[sb+1];
  int n  = e1 - e0;
  bool ok = (n <= STCAP);
  int grp = t>>4, f = t&15;
  if(t < 128) cnt[t] = 0;
  __syncthreads();

  if(ok){
    for(int i=e0+t; i<e1; i+=512) atomicAdd(&cnt[bucket2[i]>>18], 1);
    __syncthreads();
    int v = (t<128) ? cnt[t] : 0;
    int s = v;
    #pragma unroll
    for(int o=1;o<64;o<<=1){
      int u = __shfl_up(s, o, 64);
      if((t&63) >= o) s += u;
    }
    if(t == 63) wsum0 = s;
    __syncthreads();
    if(t < 128){
      int ex = s - v + ((t>=64) ? wsum0 : 0);
      coff[t] = ex; cur[t] = ex;
    }
    if(t == 0) coff[128] = n;
    __syncthreads();
    for(int i=e0+t; i<e1; i+=512){
      unsigned pkv = bucket2[i];
      int p = atomicAdd(&cur[pkv>>18], 1);
      srt[p] = pkv & 0x3FFFFu;
    }
    __syncthreads();
    for(int nd=grp; nd<128; nd+=32){
      int g = sb*128 + nd;
      if(g >= NN) continue;
      int s0 = coff[nd], s1 = coff[nd+1];
      float acc = bf2f(h1b[(size_t)g*16 + f]);     // self loop
      int j = s0;
      for(; j+4 <= s1; j+=4){
        unsigned a0=srt[j], a1=srt[j+1], a2=srt[j+2], a3=srt[j+3];
        float x0 = bf2f(h1b[a0*16 + f]);
        float x1 = bf2f(h1b[a1*16 + f]);
        float x2 = bf2f(h1b[a2*16 + f]);
        float x3 = bf2f(h1b[a3*16 + f]);
        acc += (x0+x1) + (x2+x3);
      }
      for(; j<s1; j++) acc += bf2f(h1b[srt[j]*16 + f]);
      float dvd = dinv[g];
      float r = fmaxf(dvd*acc + b1[f], 0.f);
      float p0 = r * W2[f*2+0];
      float p1 = r * W2[f*2+1];
      #pragma unroll
      for(int o=8;o>0;o>>=1){
        p0 += __shfl_xor(p0, o, 16);
        p1 += __shfl_xor(p1, o, 16);
      }
      if(f == 0){
        h2s[g*2+0] = dvd * p0;
        h2s[g*2+1] = dvd * p1;
      }
    }
  } else {
    float* accf = (float*)srt;
    for(int i=t; i<2048; i+=512) accf[i] = 0.f;
    __syncthreads();
    for(int i=e0+grp; i<e1; i+=32){
      unsigned pkv = bucket2[i];
      atomicAdd(&accf[(pkv>>18)*16 + f], bf2f(h1b[(pkv & 0x3FFFFu)*16 + f]));
    }
    __syncthreads();
    for(int nd=grp; nd<128; nd+=32){
      int g = sb*128 + nd;
      if(g >= NN) continue;
      float dvd = dinv[g];
      float acc = accf[nd*16 + f] + bf2f(h1b[(size_t)g*16 + f]);
      float r = fmaxf(dvd*acc + b1[f], 0.f);
      float p0 = r * W2[f*2+0];
      float p1 = r * W2[f*2+1];
      #pragma unroll
      for(int o=8;o>0;o>>=1){
        p0 += __shfl_xor(p0, o, 16);
        p1 += __shfl_xor(p1, o, 16);
      }
      if(f == 0){
        h2s[g*2+0] = dvd * p0;
        h2s[g*2+1] = dvd * p1;
      }
    }
  }
}

// ---------- layer-2 over compact sampled-edge list ----------
__global__ __launch_bounds__(256) void k_gacc(const unsigned* __restrict__ sampG,
                                              const int* __restrict__ sampCnt,
                                              const float* __restrict__ h2s,
                                              float* __restrict__ gacc){
  int n = min(sampCnt[0], SAMPG_CAP);
  for(int i = blockIdx.x*256 + threadIdx.x; i < n; i += gridDim.x*256){
    unsigned e = sampG[i];
    int s   = (int)(e & 0x3FFFFu);
    int idx = (int)(e >> 18);
    atomicAdd(&gacc[idx*2+0], h2s[s*2+0]);
    atomicAdd(&gacc[idx*2+1], h2s[s*2+1]);
  }
}

// ---------- post: self loop + bias + log_softmax + fused minmax ----------
__global__ __launch_bounds__(256) void k_post(const float* __restrict__ gacc,
                                              const float* __restrict__ h2s,
                                              const float* __restrict__ dinv,
                                              const float* __restrict__ b2,
                                              const float* __restrict__ t1,
                                              const float* __restrict__ t2,
                                              const float* __restrict__ t3,
                                              float* __restrict__ gout,
                                              unsigned* __restrict__ mm){
  int i = blockIdx.x*256 + threadIdx.x;
  float lo = 3.4e38f, hi = -3.4e38f;
  if(i < MR){
    int g = i*20;
    float dvd = dinv[g];
    float o0 = dvd*(gacc[i*2+0] + h2s[g*2+0]) + b2[0];
    float o1 = dvd*(gacc[i*2+1] + h2s[g*2+1]) + b2[1];
    float m = fmaxf(o0, o1);
    float lse = m + logf(expf(o0-m) + expf(o1-m));
    float g0 = o0 - lse, g1 = o1 - lse;
    gout[i*2+0] = g0; gout[i*2+1] = g1;
    float a = t1[i], bb = t2[i], c = t3[i];
    lo = fminf(fminf(a,bb), fminf(c, fminf(g0,g1)));
    hi = fmaxf(fmaxf(a,bb), fmaxf(c, fmaxf(g0,g1)));
  }
  #pragma unroll
  for(int o=32;o>0;o>>=1){
    lo = fminf(lo, __shfl_xor(lo, o, 64));
    hi = fmaxf(hi, __shfl_xor(hi, o, 64));
  }
  __shared__ float slo[4], shi[4];
  int w = threadIdx.x >> 6, l = threadIdx.x & 63;
  if(l == 0){ slo[w] = lo; shi[w] = hi; }
  __syncthreads();
  if(threadIdx.x == 0){
    for(int j=1;j<4;j++){ lo = fminf(lo, slo[j]); hi = fmaxf(hi, shi[j]); }
    atomicMin(&mm[0], enc_f(lo));
    atomicMax(&mm[1], enc_f(hi));
  }
}

// ---------- MLP head ----------
__global__ __launch_bounds__(256) void k_mlp(const float* __restrict__ t1, const float* __restrict__ t2,
                                             const float* __restrict__ t3, const float* __restrict__ g,
                                             const unsigned* __restrict__ mm,
                                             const float* __restrict__ W1, const float* __restrict__ b1,
                                             const float* __restrict__ W2, const float* __restrict__ b2,
                                             const float* __restrict__ W3, const float* __restrict__ b3,
                                             float* __restrict__ out){
  int i = blockIdx.x*256 + threadIdx.x;
  if(i >= MR) return;
  float mn = dec_f(mm[0]), mx = dec_f(mm[1]);
  float sc = 1.f/(mx - mn);
  float in[5];
  in[0] = (t1[i]   - mn)*sc;
  in[1] = (t2[i]   - mn)*sc;
  in[2] = (t3[i]   - mn)*sc;
  in[3] = (g[2*i]  - mn)*sc;
  in[4] = (g[2*i+1]- mn)*sc;
  float a[80];
  #pragma unroll
  for(int j=0;j<80;j++){
    float s = b1[j];
    #pragma unroll
    for(int k=0;k<5;k++) s += in[k]*W1[k*80+j];
    a[j] = fmaxf(s, 0.f);
  }
  float h[10];
  #pragma unroll
  for(int j=0;j<10;j++){
    float s = b2[j];
    #pragma unroll
    for(int k=0;k<80;k++) s += a[k]*W2[k*10+j];
    h[j] = fmaxf(s, 0.f);
  }
  float o = b3[0];
  #pragma unroll
  for(int k=0;k<10;k++) o += h[k]*W3[k];
  out[i] = 1.f/(1.f + expf(-o));
}

extern "C" void kernel_launch(void* const* d_in, const int* in_sizes, int n_in,
                              void* d_out, int out_size, void* d_ws, size_t ws_size,
                              hipStream_t stream) {
  (void)in_sizes; (void)n_in; (void)out_size; (void)ws_size;
  const int*   eidx    = (const int*)  d_in[0];   // [2, NE]
  const int*   src     = eidx;
  const int*   dst     = eidx + NE;
  const int4*  dst4    = (const int4*) dst;
  const float* x       = (const float*)d_in[1];   // [NN, 100]
  const float* transE  = (const float*)d_in[4];
  const float* ComplEx = (const float*)d_in[5];
  const float* path    = (const float*)d_in[6];
  const float* ghW1    = (const float*)d_in[8];
  const float* ghb1    = (const float*)d_in[9];
  const float* ghW2    = (const float*)d_in[10];
  const float* ghb2    = (const float*)d_in[11];
  const float* mW1     = (const float*)d_in[16];
  const float* mb1     = (const float*)d_in[17];
  const float* mW2     = (const float*)d_in[18];
  const float* mb2     = (const float*)d_in[19];
  const float* mW3     = (const float*)d_in[20];
  const float* mb3     = (const float*)d_in[21];
  float* out = (float*)d_out;

  // workspace carve-up (~64 MB)
  char* w = (char*)d_ws;
  size_t off = 0;
  auto alloc = [&](size_t bytes)->void*{
    void* p = w + off;
    off += (bytes + 255) & ~(size_t)255;
    return p;
  };
  unsigned* bucket1 = (unsigned*)alloc((size_t)NE*4);
  unsigned* bucket2 = (unsigned*)alloc((size_t)NE*4);
  float*    dinv    = (float*)   alloc((size_t)NN*4);
  unsigned short* h1b = (unsigned short*)alloc((size_t)NN*16*2);
  float*    h2s     = (float*)   alloc((size_t)NN*2*4);
  float*    gacc    = (float*)   alloc((size_t)MR*2*4);
  float*    gout    = (float*)   alloc((size_t)MR*2*4);
  int*      bcnt2   = (int*)     alloc((size_t)(NSB+1)*4);
  int*      bbase2  = (int*)     alloc((size_t)(NSB+1)*4);
  int*      bcur2   = (int*)     alloc((size_t)(NSB+1)*4);
  int*      bbase1  = (int*)     alloc(64*4);
  int*      bcur1   = (int*)     alloc(64*4);
  unsigned* mm      = (unsigned*)alloc(256);
  int*      sampCnt = (int*)     alloc(256);
  unsigned* sampG   = (unsigned*)alloc((size_t)SAMPG_CAP*4);

  const int SB_BLOCKS = (NE + EPB - 1)/EPB;   // 1563

  k_init   <<<(2*MR+255)/256, 256, 0, stream>>>(bcnt2, gacc, mm, sampCnt);
  k_hist   <<<1024, 256, 0, stream>>>(dst4, bcnt2);
  k_scan2  <<<1, 256, 0, stream>>>(bcnt2, bbase2, bcur2, bbase1, bcur1);
  k_stageA <<<SB_BLOCKS, 256, 0, stream>>>(src, dst, bcur1, bucket1, sampCnt, sampG);
  k_stageB <<<SB_BLOCKS, 256, 0, stream>>>(bucket1, bbase1, bcur2, bucket2);
  k_cntxw1 <<<NSB, 256, 0, stream>>>(bucket2, bbase2, x, ghW1, dinv, h1b);
  k_aggfused<<<NSB, 512, 0, stream>>>(bucket2, bbase2, dinv, h1b, ghb1, ghW2, h2s);
  k_gacc   <<<512, 256, 0, stream>>>(sampG, sampCnt, h2s, gacc);
  k_post   <<<(MR+255)/256, 256, 0, stream>>>(gacc, h2s, dinv, ghb2,
                                              transE, ComplEx, path, gout, mm);
  k_mlp    <<<(MR+255)/256, 256, 0, stream>>>(transE, ComplEx, path, gout, mm,
                                              mW1, mb1, mW2, mb2, mW3, mb3, out);
}